// Round 23
// baseline (33.969 us; speedup 1.0000x reference)
//
#include <hip/hip_runtime.h>

// MEASUREMENT ROUND: R22 best kernel verbatim (27.43us), scanx launched TWICE
// (idempotent: reads x, writes identical BP). dur delta vs 27.43 isolates
// K1's true cost to disambiguate K1~13us (big upside) vs K1~5.5us (at floor).
//
// Box filter 1024x1024 constant kernel, reflect pad (pl=pt=511, pr=pb=512).
// out = KC * H(V(x)) with V-first (linearity).
//  K1 scanx: 192 blocks x 512 threads, float4 loads; 4-row band sums in LDS
//     + per-column shuffle scan -> BP4[ch][257][1024].
//  K2 vslideh: per (ch, 4-row band): vertical sliding recurrence -> u0..u3;
//     batched 3-phase H-transform (2 syncs), XCD swizzle, padded-S LDS.

static constexpr float KC = 2.5652997311834374e-21f;
#define IMG (1024 * 1024)
#define SI(o) ((o) + ((o) >> 5))          // padded LDS index: bank-spread
#define SLEN 1057                         // SI(1024) = 1056

__device__ __forceinline__ float hwindow_p(const float* S, int o) {
    float r = 0.f;
    if (o <= 510) r += S[SI(512 - o)] - S[SI(1)];         // left mirror
    const int b0 = o > 511 ? o - 511 : 0;                 // main
    const int b1 = o + 513 < 1024 ? o + 513 : 1024;
    r += S[SI(b1)] - S[SI(b0)];
    if (o >= 512) r += S[SI(1023)] - S[SI(1534 - o)];     // right mirror
    return r;
}

// ---- K1: band sums from x + per-column scan -> BP4 ------------------------
__global__ __launch_bounds__(512) void scanx_kernel(const float* __restrict__ x,
                                                    float* __restrict__ BP) {
    __shared__ float B[257][33];
    const int t = threadIdx.x;
    const int ch = blockIdx.x >> 5, cg = blockIdx.x & 31;
    const int col0 = cg * 32;
    const int c4 = t & 7, g = t >> 3;
    const float4* xc = reinterpret_cast<const float4*>(x + (size_t)ch * IMG + col0) + c4;

    #pragma unroll
    for (int i = 0; i < 4; ++i) {
        const int band = g + 64 * i;
        const float4* p = xc + (size_t)band * 4 * 256;
        const float4 r0 = p[0], r1 = p[256], r2 = p[512], r3 = p[768];
        const int cc = 4 * c4;
        B[band][cc + 0] = (r0.x + r1.x) + (r2.x + r3.x);
        B[band][cc + 1] = (r0.y + r1.y) + (r2.y + r3.y);
        B[band][cc + 2] = (r0.z + r1.z) + (r2.z + r3.z);
        B[band][cc + 3] = (r0.w + r1.w) + (r2.w + r3.w);
    }
    __syncthreads();

    const int lane = t & 63, wv = t >> 6;
    #pragma unroll
    for (int i = 0; i < 4; ++i) {
        const int cc = wv * 4 + i;
        float v0 = B[lane][cc], v1 = B[lane + 64][cc],
              v2 = B[lane + 128][cc], v3 = B[lane + 192][cc];
        float i0 = v0, i1 = v1, i2 = v2, i3 = v3;
        #pragma unroll
        for (int off = 1; off < 64; off <<= 1) {
            float n0 = __shfl_up(i0, off), n1 = __shfl_up(i1, off);
            float n2 = __shfl_up(i2, off), n3 = __shfl_up(i3, off);
            if (lane >= off) { i0 += n0; i1 += n1; i2 += n2; i3 += n3; }
        }
        const float t0 = __shfl(i0, 63), t1 = __shfl(i1, 63), t2 = __shfl(i2, 63);
        B[lane][cc]       = i0 - v0;
        B[lane + 64][cc]  = t0 + i1 - v1;
        B[lane + 128][cc] = t0 + t1 + i2 - v2;
        B[lane + 192][cc] = t0 + t1 + t2 + i3 - v3;
        if (lane == 63) B[256][cc] = t0 + t1 + t2 + i3;   // P[1024]
    }
    __syncthreads();

    float* Bp = BP + (size_t)ch * 257 * 1024 + col0;
    #pragma unroll
    for (int i = 0; i < 17; ++i) {
        const int idx = i * 512 + t;
        if (idx < 257 * 32) {
            const int k = idx >> 5, cw = idx & 31;
            Bp[(size_t)k * 1024 + cw] = B[k][cw];
        }
    }
}

// ---- K2: vertical slide + batched in-block horizontal. grid 1536 ----------
__global__ __launch_bounds__(256) void vslideh_kernel(const float* __restrict__ x,
                                                      const float* __restrict__ BP,
                                                      float* __restrict__ out) {
    __shared__ float S[4][SLEN];
    __shared__ float wtot[4][4];
    const int t = threadIdx.x;
    const int swz = (blockIdx.x & 7) * 192 + (blockIdx.x >> 3);
    const int ch = swz >> 8, band = swz & 255;
    const int O = band * 4;
    const float* xc = x + (size_t)ch * IMG;
    const float* Bc = BP + (size_t)ch * 257 * 1024;
    float* oc = out + (size_t)ch * IMG;

    #define LD4(base, row) (reinterpret_cast<const float4*>((base) + (size_t)(row) * 1024)[t])

    float4 u0, u1, u2, u3;
    if (band < 128) {
        const float4 bA = LD4(Bc, (512 - O) >> 2);
        const float4 x0 = LD4(xc, 0);
        const float4 bB = LD4(Bc, (512 + O) >> 2);
        const float4 xb = LD4(xc, O + 512);
        u0.x = bA.x - x0.x + bB.x + xb.x;
        u0.y = bA.y - x0.y + bB.y + xb.y;
        u0.z = bA.z - x0.z + bB.z + xb.z;
        u0.w = bA.w - x0.w + bB.w + xb.w;
        {
            const float4 a = LD4(xc, O + 513), s = LD4(xc, 511 - O);
            u1.x = u0.x + a.x - s.x; u1.y = u0.y + a.y - s.y;
            u1.z = u0.z + a.z - s.z; u1.w = u0.w + a.w - s.w;
        }
        {
            const float4 a = LD4(xc, O + 514), s = LD4(xc, 510 - O);
            u2.x = u1.x + a.x - s.x; u2.y = u1.y + a.y - s.y;
            u2.z = u1.z + a.z - s.z; u2.w = u1.w + a.w - s.w;
        }
        if (band == 127) {
            u3 = LD4(Bc, 256);                       // U[511] = P[1024]
        } else {
            const float4 a = LD4(xc, O + 515), s = LD4(xc, 509 - O);
            u3.x = u2.x + a.x - s.x; u3.y = u2.y + a.y - s.y;
            u3.z = u2.z + a.z - s.z; u3.w = u2.w + a.w - s.w;
        }
    } else {
        const float4 bt = LD4(Bc, 256);
        const float4 bA = LD4(Bc, (O - 512) >> 2);
        const float4 xm = LD4(xc, 1023);
        const float4 bB = LD4(Bc, (1536 - O) >> 2);
        const float4 xf = LD4(xc, 1535 - O);
        float4 acc;
        acc.x = bt.x - bA.x + (bt.x - xm.x) - (bB.x - xf.x);
        acc.y = bt.y - bA.y + (bt.y - xm.y) - (bB.y - xf.y);
        acc.z = bt.z - bA.z + (bt.z - xm.z) - (bB.z - xf.z);
        acc.w = bt.w - bA.w + (bt.w - xm.w) - (bB.w - xf.w);
        {
            const float4 a = LD4(xc, 1534 - O), s = LD4(xc, O - 512);
            u0.x = acc.x + a.x - s.x; u0.y = acc.y + a.y - s.y;
            u0.z = acc.z + a.z - s.z; u0.w = acc.w + a.w - s.w;
        }
        {
            const float4 a = LD4(xc, 1533 - O), s = LD4(xc, O - 511);
            u1.x = u0.x + a.x - s.x; u1.y = u0.y + a.y - s.y;
            u1.z = u0.z + a.z - s.z; u1.w = u0.w + a.w - s.w;
        }
        {
            const float4 a = LD4(xc, 1532 - O), s = LD4(xc, O - 510);
            u2.x = u1.x + a.x - s.x; u2.y = u1.y + a.y - s.y;
            u2.z = u1.z + a.z - s.z; u2.w = u1.w + a.w - s.w;
        }
        {
            const float4 a = LD4(xc, 1531 - O), s = LD4(xc, O - 509);
            u3.x = u2.x + a.x - s.x; u3.y = u2.y + a.y - s.y;
            u3.z = u2.z + a.z - s.z; u3.w = u2.w + a.w - s.w;
        }
    }
    #undef LD4

    const int lane = t & 63, wave = t >> 6;

    const float a0 = u0.x, a1 = a0 + u0.y, a2 = a1 + u0.z, a3 = a2 + u0.w;
    const float b0 = u1.x, b1 = b0 + u1.y, b2 = b1 + u1.z, b3 = b2 + u1.w;
    const float c0 = u2.x, c1 = c0 + u2.y, c2 = c1 + u2.z, c3 = c2 + u2.w;
    const float d0 = u3.x, d1 = d0 + u3.y, d2 = d1 + u3.z, d3 = d2 + u3.w;
    float iA = a3, iB = b3, iC = c3, iD = d3;
    #pragma unroll
    for (int off = 1; off < 64; off <<= 1) {
        float nA = __shfl_up(iA, off), nB = __shfl_up(iB, off);
        float nC = __shfl_up(iC, off), nD = __shfl_up(iD, off);
        if (lane >= off) { iA += nA; iB += nB; iC += nC; iD += nD; }
    }
    if (lane == 63) {
        wtot[0][wave] = iA; wtot[1][wave] = iB;
        wtot[2][wave] = iC; wtot[3][wave] = iD;
    }
    __syncthreads();

    float wA = 0.f, wB = 0.f, wC = 0.f, wD = 0.f;
    for (int w = 0; w < wave; ++w) {
        wA += wtot[0][w]; wB += wtot[1][w];
        wC += wtot[2][w]; wD += wtot[3][w];
    }
    const float eA = wA + iA - a3;
    const float eB = wB + iB - b3;
    const float eC = wC + iC - c3;
    const float eD = wD + iD - d3;
    const int ox = 4 * t;
    S[0][SI(ox + 0)] = eA;      S[0][SI(ox + 1)] = eA + a0;
    S[0][SI(ox + 2)] = eA + a1; S[0][SI(ox + 3)] = eA + a2;
    S[1][SI(ox + 0)] = eB;      S[1][SI(ox + 1)] = eB + b0;
    S[1][SI(ox + 2)] = eB + b1; S[1][SI(ox + 3)] = eB + b2;
    S[2][SI(ox + 0)] = eC;      S[2][SI(ox + 1)] = eC + c0;
    S[2][SI(ox + 2)] = eC + c1; S[2][SI(ox + 3)] = eC + c2;
    S[3][SI(ox + 0)] = eD;      S[3][SI(ox + 1)] = eD + d0;
    S[3][SI(ox + 2)] = eD + d1; S[3][SI(ox + 3)] = eD + d2;
    if (t == 255) {
        S[0][SI(1024)] = eA + a3; S[1][SI(1024)] = eB + b3;
        S[2][SI(1024)] = eC + c3; S[3][SI(1024)] = eD + d3;
    }
    __syncthreads();

    #pragma unroll
    for (int j = 0; j < 4; ++j) {
        float4 o;
        o.x = KC * hwindow_p(S[j], ox + 0);
        o.y = KC * hwindow_p(S[j], ox + 1);
        o.z = KC * hwindow_p(S[j], ox + 2);
        o.w = KC * hwindow_p(S[j], ox + 3);
        reinterpret_cast<float4*>(oc + (size_t)(O + j) * 1024)[t] = o;
    }
}

extern "C" void kernel_launch(void* const* d_in, const int* in_sizes, int n_in,
                              void* d_out, int out_size, void* d_ws, size_t ws_size,
                              hipStream_t stream) {
    const float* x = (const float*)d_in[2];
    float* out = (float*)d_out;
    float* BP = (float*)d_ws;                        // 6*257*1024 floats
    scanx_kernel<<<192, 512, 0, stream>>>(x, BP);
    scanx_kernel<<<192, 512, 0, stream>>>(x, BP);    // measurement: 2nd
    vslideh_kernel<<<1536, 256, 0, stream>>>(x, BP, out);
}

// Round 24
// 27.425 us; speedup vs baseline: 1.2386x; 1.2386x over previous
//
#include <hip/hip_runtime.h>

// FINAL CONFIGURATION (R22 best, 27.43us): measurement double-launch removed.
//
// Box filter 1024x1024 constant kernel, reflect pad (pl=pt=511, pr=pb=512).
// out = KC * H(V(x)) with V-first (linearity). 2-dispatch pipeline:
//  K1 scanx (~5us, at 6.3TB/s wire for its 31MB): 192 blocks x 512 threads,
//     float4 loads; 4-row band sums in LDS + per-column shuffle scan ->
//     BP4[ch][257][1024], BP4[k]=P[4k], BP4[256]=P[1024].
//  K2 vslideh (~13.5us, 6.4TB/s effective for its 86MB): per (ch, 4-row
//     band): vertical sliding recurrence gives u0..u3 in registers; one
//     batched 3-phase H-transform (2 syncs). XCD swizzle (R21, +1.5us):
//     swz=(b&7)*192+(b>>3) makes each XCD's blocks channel-contiguous
//     (L2-resident). Padded-S LDS (R22, +0.6us): SI(o)=o+(o>>5) turns the
//     stride-4 lane pattern from 8-way bank conflict into free 2-way.
//    U[o] = U[o-1] + x[o+512] - x[512-o]   (1 <= o <= 510)
//    U[511] = P[1024]
//    U[o] = U[o-1] - x[o-512] + x[1534-o]  (513 <= o <= 1023)
// Measured component budget: K1 5 + boundary 1.5 + K2 13.5 + launch ~7.5.
// Falsified levers: sync count (R14/R19), read-vs-TLP trades (R15/R20),
// LDS read stride (R16), vectorization width (R9), mirror pairing (R15).

static constexpr float KC = 2.5652997311834374e-21f;
#define IMG (1024 * 1024)
#define SI(o) ((o) + ((o) >> 5))          // padded LDS index: bank-spread
#define SLEN 1057                         // SI(1024) = 1056

__device__ __forceinline__ float hwindow_p(const float* S, int o) {
    float r = 0.f;
    if (o <= 510) r += S[SI(512 - o)] - S[SI(1)];         // left mirror
    const int b0 = o > 511 ? o - 511 : 0;                 // main
    const int b1 = o + 513 < 1024 ? o + 513 : 1024;
    r += S[SI(b1)] - S[SI(b0)];
    if (o >= 512) r += S[SI(1023)] - S[SI(1534 - o)];     // right mirror
    return r;
}

// ---- K1: band sums from x + per-column scan -> BP4 ------------------------
__global__ __launch_bounds__(512) void scanx_kernel(const float* __restrict__ x,
                                                    float* __restrict__ BP) {
    __shared__ float B[257][33];
    const int t = threadIdx.x;
    const int ch = blockIdx.x >> 5, cg = blockIdx.x & 31;
    const int col0 = cg * 32;
    const int c4 = t & 7, g = t >> 3;
    const float4* xc = reinterpret_cast<const float4*>(x + (size_t)ch * IMG + col0) + c4;

    #pragma unroll
    for (int i = 0; i < 4; ++i) {
        const int band = g + 64 * i;
        const float4* p = xc + (size_t)band * 4 * 256;
        const float4 r0 = p[0], r1 = p[256], r2 = p[512], r3 = p[768];
        const int cc = 4 * c4;
        B[band][cc + 0] = (r0.x + r1.x) + (r2.x + r3.x);
        B[band][cc + 1] = (r0.y + r1.y) + (r2.y + r3.y);
        B[band][cc + 2] = (r0.z + r1.z) + (r2.z + r3.z);
        B[band][cc + 3] = (r0.w + r1.w) + (r2.w + r3.w);
    }
    __syncthreads();

    const int lane = t & 63, wv = t >> 6;
    #pragma unroll
    for (int i = 0; i < 4; ++i) {
        const int cc = wv * 4 + i;
        float v0 = B[lane][cc], v1 = B[lane + 64][cc],
              v2 = B[lane + 128][cc], v3 = B[lane + 192][cc];
        float i0 = v0, i1 = v1, i2 = v2, i3 = v3;
        #pragma unroll
        for (int off = 1; off < 64; off <<= 1) {
            float n0 = __shfl_up(i0, off), n1 = __shfl_up(i1, off);
            float n2 = __shfl_up(i2, off), n3 = __shfl_up(i3, off);
            if (lane >= off) { i0 += n0; i1 += n1; i2 += n2; i3 += n3; }
        }
        const float t0 = __shfl(i0, 63), t1 = __shfl(i1, 63), t2 = __shfl(i2, 63);
        B[lane][cc]       = i0 - v0;
        B[lane + 64][cc]  = t0 + i1 - v1;
        B[lane + 128][cc] = t0 + t1 + i2 - v2;
        B[lane + 192][cc] = t0 + t1 + t2 + i3 - v3;
        if (lane == 63) B[256][cc] = t0 + t1 + t2 + i3;   // P[1024]
    }
    __syncthreads();

    float* Bp = BP + (size_t)ch * 257 * 1024 + col0;
    #pragma unroll
    for (int i = 0; i < 17; ++i) {
        const int idx = i * 512 + t;
        if (idx < 257 * 32) {
            const int k = idx >> 5, cw = idx & 31;
            Bp[(size_t)k * 1024 + cw] = B[k][cw];
        }
    }
}

// ---- K2: vertical slide + batched in-block horizontal. grid 1536 ----------
__global__ __launch_bounds__(256) void vslideh_kernel(const float* __restrict__ x,
                                                      const float* __restrict__ BP,
                                                      float* __restrict__ out) {
    __shared__ float S[4][SLEN];
    __shared__ float wtot[4][4];
    const int t = threadIdx.x;
    const int swz = (blockIdx.x & 7) * 192 + (blockIdx.x >> 3);
    const int ch = swz >> 8, band = swz & 255;
    const int O = band * 4;
    const float* xc = x + (size_t)ch * IMG;
    const float* Bc = BP + (size_t)ch * 257 * 1024;
    float* oc = out + (size_t)ch * IMG;

    #define LD4(base, row) (reinterpret_cast<const float4*>((base) + (size_t)(row) * 1024)[t])

    float4 u0, u1, u2, u3;
    if (band < 128) {
        const float4 bA = LD4(Bc, (512 - O) >> 2);
        const float4 x0 = LD4(xc, 0);
        const float4 bB = LD4(Bc, (512 + O) >> 2);
        const float4 xb = LD4(xc, O + 512);
        u0.x = bA.x - x0.x + bB.x + xb.x;
        u0.y = bA.y - x0.y + bB.y + xb.y;
        u0.z = bA.z - x0.z + bB.z + xb.z;
        u0.w = bA.w - x0.w + bB.w + xb.w;
        {
            const float4 a = LD4(xc, O + 513), s = LD4(xc, 511 - O);
            u1.x = u0.x + a.x - s.x; u1.y = u0.y + a.y - s.y;
            u1.z = u0.z + a.z - s.z; u1.w = u0.w + a.w - s.w;
        }
        {
            const float4 a = LD4(xc, O + 514), s = LD4(xc, 510 - O);
            u2.x = u1.x + a.x - s.x; u2.y = u1.y + a.y - s.y;
            u2.z = u1.z + a.z - s.z; u2.w = u1.w + a.w - s.w;
        }
        if (band == 127) {
            u3 = LD4(Bc, 256);                       // U[511] = P[1024]
        } else {
            const float4 a = LD4(xc, O + 515), s = LD4(xc, 509 - O);
            u3.x = u2.x + a.x - s.x; u3.y = u2.y + a.y - s.y;
            u3.z = u2.z + a.z - s.z; u3.w = u2.w + a.w - s.w;
        }
    } else {
        const float4 bt = LD4(Bc, 256);
        const float4 bA = LD4(Bc, (O - 512) >> 2);
        const float4 xm = LD4(xc, 1023);
        const float4 bB = LD4(Bc, (1536 - O) >> 2);
        const float4 xf = LD4(xc, 1535 - O);
        float4 acc;
        acc.x = bt.x - bA.x + (bt.x - xm.x) - (bB.x - xf.x);
        acc.y = bt.y - bA.y + (bt.y - xm.y) - (bB.y - xf.y);
        acc.z = bt.z - bA.z + (bt.z - xm.z) - (bB.z - xf.z);
        acc.w = bt.w - bA.w + (bt.w - xm.w) - (bB.w - xf.w);
        {
            const float4 a = LD4(xc, 1534 - O), s = LD4(xc, O - 512);
            u0.x = acc.x + a.x - s.x; u0.y = acc.y + a.y - s.y;
            u0.z = acc.z + a.z - s.z; u0.w = acc.w + a.w - s.w;
        }
        {
            const float4 a = LD4(xc, 1533 - O), s = LD4(xc, O - 511);
            u1.x = u0.x + a.x - s.x; u1.y = u0.y + a.y - s.y;
            u1.z = u0.z + a.z - s.z; u1.w = u0.w + a.w - s.w;
        }
        {
            const float4 a = LD4(xc, 1532 - O), s = LD4(xc, O - 510);
            u2.x = u1.x + a.x - s.x; u2.y = u1.y + a.y - s.y;
            u2.z = u1.z + a.z - s.z; u2.w = u1.w + a.w - s.w;
        }
        {
            const float4 a = LD4(xc, 1531 - O), s = LD4(xc, O - 509);
            u3.x = u2.x + a.x - s.x; u3.y = u2.y + a.y - s.y;
            u3.z = u2.z + a.z - s.z; u3.w = u2.w + a.w - s.w;
        }
    }
    #undef LD4

    const int lane = t & 63, wave = t >> 6;

    const float a0 = u0.x, a1 = a0 + u0.y, a2 = a1 + u0.z, a3 = a2 + u0.w;
    const float b0 = u1.x, b1 = b0 + u1.y, b2 = b1 + u1.z, b3 = b2 + u1.w;
    const float c0 = u2.x, c1 = c0 + u2.y, c2 = c1 + u2.z, c3 = c2 + u2.w;
    const float d0 = u3.x, d1 = d0 + u3.y, d2 = d1 + u3.z, d3 = d2 + u3.w;
    float iA = a3, iB = b3, iC = c3, iD = d3;
    #pragma unroll
    for (int off = 1; off < 64; off <<= 1) {
        float nA = __shfl_up(iA, off), nB = __shfl_up(iB, off);
        float nC = __shfl_up(iC, off), nD = __shfl_up(iD, off);
        if (lane >= off) { iA += nA; iB += nB; iC += nC; iD += nD; }
    }
    if (lane == 63) {
        wtot[0][wave] = iA; wtot[1][wave] = iB;
        wtot[2][wave] = iC; wtot[3][wave] = iD;
    }
    __syncthreads();

    float wA = 0.f, wB = 0.f, wC = 0.f, wD = 0.f;
    for (int w = 0; w < wave; ++w) {
        wA += wtot[0][w]; wB += wtot[1][w];
        wC += wtot[2][w]; wD += wtot[3][w];
    }
    const float eA = wA + iA - a3;
    const float eB = wB + iB - b3;
    const float eC = wC + iC - c3;
    const float eD = wD + iD - d3;
    const int ox = 4 * t;
    S[0][SI(ox + 0)] = eA;      S[0][SI(ox + 1)] = eA + a0;
    S[0][SI(ox + 2)] = eA + a1; S[0][SI(ox + 3)] = eA + a2;
    S[1][SI(ox + 0)] = eB;      S[1][SI(ox + 1)] = eB + b0;
    S[1][SI(ox + 2)] = eB + b1; S[1][SI(ox + 3)] = eB + b2;
    S[2][SI(ox + 0)] = eC;      S[2][SI(ox + 1)] = eC + c0;
    S[2][SI(ox + 2)] = eC + c1; S[2][SI(ox + 3)] = eC + c2;
    S[3][SI(ox + 0)] = eD;      S[3][SI(ox + 1)] = eD + d0;
    S[3][SI(ox + 2)] = eD + d1; S[3][SI(ox + 3)] = eD + d2;
    if (t == 255) {
        S[0][SI(1024)] = eA + a3; S[1][SI(1024)] = eB + b3;
        S[2][SI(1024)] = eC + c3; S[3][SI(1024)] = eD + d3;
    }
    __syncthreads();

    #pragma unroll
    for (int j = 0; j < 4; ++j) {
        float4 o;
        o.x = KC * hwindow_p(S[j], ox + 0);
        o.y = KC * hwindow_p(S[j], ox + 1);
        o.z = KC * hwindow_p(S[j], ox + 2);
        o.w = KC * hwindow_p(S[j], ox + 3);
        reinterpret_cast<float4*>(oc + (size_t)(O + j) * 1024)[t] = o;
    }
}

extern "C" void kernel_launch(void* const* d_in, const int* in_sizes, int n_in,
                              void* d_out, int out_size, void* d_ws, size_t ws_size,
                              hipStream_t stream) {
    const float* x = (const float*)d_in[2];
    float* out = (float*)d_out;
    float* BP = (float*)d_ws;                        // 6*257*1024 floats
    scanx_kernel<<<192, 512, 0, stream>>>(x, BP);
    vslideh_kernel<<<1536, 256, 0, stream>>>(x, BP, out);
}